// Round 7
// baseline (107.057 us; speedup 1.0000x reference)
//
#include <hip/hip_runtime.h>

typedef float v4f __attribute__((ext_vector_type(4)));

#define BB 8
#define NN 8192
#define MM 8192
#define SPLIT 32
#define MCHUNK (MM / SPLIT)  // 256 xyz2 points staged per block
#define P 16                 // xyz1 points per thread
#define TPB 128              // 2 waves per block

// ws layout (SoA xyz2 pack + partial mins):
//   [0, 1M)   : xs/ys/zs/w2[B*M] SoA
//   [1M, 9M)  : pmins[SPLIT][B*N]
#define ASZ (BB * MM)

__global__ __launch_bounds__(256) void chamfer_pack(const float* __restrict__ xyz2,
                                                    float* __restrict__ xs, float* __restrict__ ys,
                                                    float* __restrict__ zs, float* __restrict__ w2,
                                                    float* __restrict__ out) {
    int idx = blockIdx.x * 256 + threadIdx.x;  // 0 .. B*M-1
    if (idx == 0) out[0] = 0.0f;
    float x = xyz2[idx * 3 + 0];
    float y = xyz2[idx * 3 + 1];
    float z = xyz2[idx * 3 + 2];
    xs[idx] = x; ys[idx] = y; zs[idx] = z;
    w2[idx] = fmaf(x, x, fmaf(y, y, z * z));
}

__global__ __launch_bounds__(TPB, 3) void chamfer_min(const float* __restrict__ xyz1,
                                                      const float* __restrict__ xs,
                                                      const float* __restrict__ ys,
                                                      const float* __restrict__ zs,
                                                      const float* __restrict__ w2,
                                                      float* __restrict__ pmins) {
    __shared__ float sx[MCHUNK], sy[MCHUNK], sz[MCHUNK], sw[MCHUNK];

    // grid = 1024: low 5 bits = tile over B*N (32 tiles x 2048 pts), high 5 = m-split
    int tile  = blockIdx.x & 31;
    int split = blockIdx.x >> 5;
    int batch = tile >> 2;   // 8 batches
    int nt    = tile & 3;    // 4 tiles of 2048 points per batch
    int g = nt * TPB + threadIdx.x;  // this thread's 16-point group, 0..511

    // ---- stage SoA chunk -> LDS (1 float2 per array per thread, coalesced) ----
    {
        int t = threadIdx.x;
        size_t o = (size_t)batch * MM + (size_t)split * MCHUNK + 2 * t;
        *(float2*)&sx[2 * t] = *(const float2*)(xs + o);
        *(float2*)&sy[2 * t] = *(const float2*)(ys + o);
        *(float2*)&sz[2 * t] = *(const float2*)(zs + o);
        *(float2*)&sw[2 * t] = *(const float2*)(w2 + o);
    }

    // ---- load this thread's 16 xyz1 points (48 floats = 12 float4) ----
    const float4* q = (const float4*)(xyz1 + ((size_t)batch * NN + (size_t)g * P) * 3);
    float f[48];
    float4* f4 = (float4*)f;
#pragma unroll
    for (int t = 0; t < 12; ++t) f4[t] = q[t];

    float bx[P], by[P], bz[P], x2[P], m[P];
#pragma unroll
    for (int p = 0; p < P; ++p) {
        float ax = f[3 * p + 0], ay = f[3 * p + 1], az = f[3 * p + 2];
        x2[p] = fmaf(ax, ax, fmaf(ay, ay, az * az));
        bx[p] = -2.0f * ax;
        by[p] = -2.0f * ay;
        bz[p] = -2.0f * az;
        m[p] = 1e30f;
    }

    __syncthreads();

    // ---- main loop: 4 j's/iter via SoA b128 broadcast reads; min3 tree ----
#pragma unroll 2
    for (int j = 0; j < MCHUNK; j += 4) {
        v4f wx = *(const v4f*)&sx[j];
        v4f wy = *(const v4f*)&sy[j];
        v4f wz = *(const v4f*)&sz[j];
        v4f ww = *(const v4f*)&sw[j];
#pragma unroll
        for (int p = 0; p < P; ++p) {
            float d0 = fmaf(bx[p], wx.x, fmaf(by[p], wy.x, fmaf(bz[p], wz.x, ww.x)));
            float d1 = fmaf(bx[p], wx.y, fmaf(by[p], wy.y, fmaf(bz[p], wz.y, ww.y)));
            float d2 = fmaf(bx[p], wx.z, fmaf(by[p], wy.z, fmaf(bz[p], wz.z, ww.z)));
            float d3 = fmaf(bx[p], wx.w, fmaf(by[p], wy.w, fmaf(bz[p], wz.w, ww.w)));
            // tree shape -> v_min_f32 x2 + v_min3_f32 (3 slots, not 4)
            m[p] = fminf(fminf(fminf(d0, d1), fminf(d2, d3)), m[p]);
        }
    }

    // ---- epilogue: add x2, store 16 floats as 4 float4 ----
    float r[P];
#pragma unroll
    for (int p = 0; p < P; ++p) r[p] = x2[p] + m[p];
    size_t base = (size_t)split * (BB * NN) + (size_t)batch * NN + (size_t)g * P;
    float4* dst = (float4*)(pmins + base);
#pragma unroll
    for (int t = 0; t < 4; ++t) dst[t] = ((float4*)r)[t];
}

__global__ __launch_bounds__(256) void chamfer_reduce(const float* __restrict__ pmins,
                                                      float* __restrict__ out) {
    int i = blockIdx.x * 256 + threadIdx.x;  // grid 256 blocks, 0..65535
    float m = pmins[i];
#pragma unroll
    for (int sp = 1; sp < SPLIT; ++sp)
        m = fminf(m, pmins[(size_t)sp * (BB * NN) + i]);
    float s = m;
#pragma unroll
    for (int off = 32; off > 0; off >>= 1) s += __shfl_down(s, off);
    __shared__ float ls[4];
    int lane = threadIdx.x & 63, wv = threadIdx.x >> 6;
    if (lane == 0) ls[wv] = s;
    __syncthreads();
    if (threadIdx.x == 0) {
        float t = (ls[0] + ls[1]) + (ls[2] + ls[3]);
        atomicAdd(out, t * (1.0f / (float)(BB * NN)));
    }
}

extern "C" void kernel_launch(void* const* d_in, const int* in_sizes, int n_in,
                              void* d_out, int out_size, void* d_ws, size_t ws_size,
                              hipStream_t stream) {
    const float* xyz1 = (const float*)d_in[0];
    const float* xyz2 = (const float*)d_in[1];
    float* out = (float*)d_out;
    float* xs = (float*)d_ws;
    float* ys = xs + ASZ;
    float* zs = ys + ASZ;
    float* w2 = zs + ASZ;
    float* pmins = w2 + ASZ;

    chamfer_pack<<<(BB * MM) / 256, 256, 0, stream>>>(xyz2, xs, ys, zs, w2, out);
    chamfer_min<<<(BB * NN / (P * TPB)) * SPLIT, TPB, 0, stream>>>(xyz1, xs, ys, zs, w2, pmins);
    chamfer_reduce<<<(BB * NN) / 256, 256, 0, stream>>>(pmins, out);
}